// Round 2
// baseline (2216.104 us; speedup 1.0000x reference)
//
#include <hip/hip_runtime.h>
#include <math.h>

// Problem constants (CACombiner)
#define B_   8
#define C_   512
#define L_   4096
#define H_   8
#define DK_  64
#define C2_  1024

// ---------------------------------------------------------------------------
// Tiled fp32 GEMM: out[b,o,l] = act( sum_c W[o,c]*in[b,c,l] + bias[o] (+res) )
// W: [O,Cin] row-major, in/out/res: [B, *, L_] channels-first.
// Tile: 64(o) x 64(l), BC=16, 256 threads, 4x4 microtile per thread.
// ---------------------------------------------------------------------------
template<int ACT, bool HAS_RES>
__global__ __launch_bounds__(256) void conv1x1_kernel(
    const float* __restrict__ W, const float* __restrict__ in,
    const float* __restrict__ bias, const float* __restrict__ res,
    float* __restrict__ out, int O, int Cin)
{
    const int b  = blockIdx.z;
    const int o0 = blockIdx.y << 6;
    const int l0 = blockIdx.x << 6;
    const int tid = threadIdx.x;
    const int tx = tid & 15;       // l / 4
    const int ty = tid >> 4;       // o / 4

    __shared__ float sW[16][68];   // sW[c][o], padded
    __shared__ float sZ[16][64];   // sZ[c][l]

    float acc[4][4] = {};

    const int zc = tid >> 4;            // 0..15  (c row for Z staging)
    const int zl = (tid & 15) << 2;     // 0..60  (l col, float4)
    const int wo = tid >> 2;            // 0..63  (o row for W staging)
    const int wc = (tid & 3) << 2;      // 0..12  (c col, float4)

    const float* inp = in + (size_t)b * Cin * L_ + l0;
    const float* wp  = W + (size_t)(o0 + wo) * Cin;

    for (int c0 = 0; c0 < Cin; c0 += 16) {
        const float4 zv = *(const float4*)(inp + (size_t)(c0 + zc) * L_ + zl);
        const float4 wv = *(const float4*)(wp + c0 + wc);
        __syncthreads();
        *(float4*)&sZ[zc][zl] = zv;
        sW[wc+0][wo] = wv.x; sW[wc+1][wo] = wv.y;
        sW[wc+2][wo] = wv.z; sW[wc+3][wo] = wv.w;
        __syncthreads();
#pragma unroll
        for (int kk = 0; kk < 16; ++kk) {
            const float4 a4 = *(const float4*)&sW[kk][ty << 2];
            const float4 z4 = *(const float4*)&sZ[kk][tx << 2];
            const float av[4] = {a4.x, a4.y, a4.z, a4.w};
            const float zv4[4] = {z4.x, z4.y, z4.z, z4.w};
#pragma unroll
            for (int i = 0; i < 4; ++i)
#pragma unroll
                for (int j = 0; j < 4; ++j)
                    acc[i][j] = fmaf(av[i], zv4[j], acc[i][j]);
        }
    }

#pragma unroll
    for (int i = 0; i < 4; ++i) {
        const int o = o0 + (ty << 2) + i;
        const float bo = bias[o];
        const size_t base = ((size_t)b * O + o) * L_ + l0 + (tx << 2);
        float vv[4];
#pragma unroll
        for (int j = 0; j < 4; ++j) {
            float t = acc[i][j] + bo;
            if (HAS_RES) t += res[base + j];
            if (ACT == 1) t = (t > 0.f) ? t : (__expf(t) - 1.f);  // ELU
            vv[j] = t;
        }
        float4 o4 = {vv[0], vv[1], vv[2], vv[3]};
        *(float4*)(out + base) = o4;
    }
}

// ---------------------------------------------------------------------------
// Softmax over L (rows of length 4096). One block per row (B_*C_ rows).
// ---------------------------------------------------------------------------
__device__ __forceinline__ float wave_max(float v) {
#pragma unroll
    for (int o = 32; o > 0; o >>= 1) v = fmaxf(v, __shfl_xor(v, o));
    return v;
}
__device__ __forceinline__ float wave_sum(float v) {
#pragma unroll
    for (int o = 32; o > 0; o >>= 1) v += __shfl_xor(v, o);
    return v;
}

__global__ __launch_bounds__(256) void softmax_l_kernel(float* __restrict__ data)
{
    const size_t row = blockIdx.x;
    float* p = data + row * L_;
    const int tid = threadIdx.x;
    const int wid = tid >> 6, lane = tid & 63;
    __shared__ float redm[4], reds[4];

    float v[16];
    float m = -3.0e38f;
#pragma unroll
    for (int i = 0; i < 16; ++i) { v[i] = p[tid + (i << 8)]; m = fmaxf(m, v[i]); }
    m = wave_max(m);
    if (lane == 0) redm[wid] = m;
    __syncthreads();
    m = fmaxf(fmaxf(redm[0], redm[1]), fmaxf(redm[2], redm[3]));

    float s = 0.f;
#pragma unroll
    for (int i = 0; i < 16; ++i) { v[i] = __expf(v[i] - m); s += v[i]; }
    s = wave_sum(s);
    if (lane == 0) reds[wid] = s;
    __syncthreads();
    s = reds[0] + reds[1] + reds[2] + reds[3];
    const float inv = 1.f / s;
#pragma unroll
    for (int i = 0; i < 16; ++i) p[tid + (i << 8)] = v[i] * inv;
}

// ---------------------------------------------------------------------------
// Softmax over DK=64 channels (axis=2 of [B,H,DK,L]). Thread per l.
// ---------------------------------------------------------------------------
__global__ __launch_bounds__(256) void softmax_c_kernel(float* __restrict__ q)
{
    const int l  = blockIdx.x * 256 + threadIdx.x;
    const int bh = blockIdx.y;          // b*H + h
    float* p = q + (size_t)bh * DK_ * L_ + l;
    float v[64];
    float m = -3.0e38f;
#pragma unroll
    for (int d = 0; d < 64; ++d) { v[d] = p[(size_t)d * L_]; m = fmaxf(m, v[d]); }
    float s = 0.f;
#pragma unroll
    for (int d = 0; d < 64; ++d) { v[d] = __expf(v[d] - m); s += v[d]; }
    const float inv = 1.f / s;
#pragma unroll
    for (int d = 0; d < 64; ++d) p[(size_t)d * L_] = v[d] * inv;
}

// ---------------------------------------------------------------------------
// Zero a float buffer (graph-capture-safe replacement for hipMemsetAsync).
// ---------------------------------------------------------------------------
__global__ __launch_bounds__(256) void zero_kernel(float* __restrict__ p, int n4)
{
    const int i = blockIdx.x * 256 + threadIdx.x;
    if (i < n4) {
        float4 z = {0.f, 0.f, 0.f, 0.f};
        *(float4*)(p + 4 * (size_t)i) = z;
    }
}

// ---------------------------------------------------------------------------
// ctx[b,h,k,v] = sum_l kh[b,h,k,l]*vh[b,h,v,l].  Grid (8 l-splits, B*H).
// atomicAdd accumulate; ctx pre-zeroed.
// ---------------------------------------------------------------------------
__global__ __launch_bounds__(256) void ctx_kernel(
    const float* __restrict__ kh, const float* __restrict__ vh,
    float* __restrict__ ctx)
{
    const int bh = blockIdx.y;
    const int l0 = blockIdx.x * 512;
    const float* kp = kh + (size_t)bh * DK_ * L_;
    const float* vp = vh + (size_t)bh * DK_ * L_;
    __shared__ float sK[64][33];
    __shared__ float sV[64][33];
    const int tid = threadIdx.x;
    const int kq = (tid >> 4) << 2, vq = (tid & 15) << 2;
    const int r  = tid >> 2,  cc = (tid & 3) << 3;
    float acc[4][4] = {};

    for (int lt = 0; lt < 512; lt += 32) {
        const float* kpp = kp + (size_t)r * L_ + l0 + lt + cc;
        const float* vpp = vp + (size_t)r * L_ + l0 + lt + cc;
        float kv[8], vv[8];
#pragma unroll
        for (int i = 0; i < 8; ++i) { kv[i] = kpp[i]; vv[i] = vpp[i]; }
        __syncthreads();
#pragma unroll
        for (int i = 0; i < 8; ++i) { sK[r][cc + i] = kv[i]; sV[r][cc + i] = vv[i]; }
        __syncthreads();
#pragma unroll
        for (int ll = 0; ll < 32; ++ll) {
            float a[4], bb[4];
#pragma unroll
            for (int i = 0; i < 4; ++i) a[i]  = sK[kq + i][ll];
#pragma unroll
            for (int j = 0; j < 4; ++j) bb[j] = sV[vq + j][ll];
#pragma unroll
            for (int i = 0; i < 4; ++i)
#pragma unroll
                for (int j = 0; j < 4; ++j)
                    acc[i][j] = fmaf(a[i], bb[j], acc[i][j]);
        }
    }
    float* cp = ctx + (size_t)bh * 64 * 64;
#pragma unroll
    for (int i = 0; i < 4; ++i)
#pragma unroll
        for (int j = 0; j < 4; ++j)
            atomicAdd(&cp[(kq + i) * 64 + (vq + j)], acc[i][j]);
}

// ---------------------------------------------------------------------------
// att[b, h*64+dv, l] = sum_k ctx[b,h,k,dv] * qh[b,h,k,l].  Grid (L/64, B*H).
// SAFE IN-PLACE (att == q): each block reads exactly the q region it writes,
// staged fully into LDS behind a barrier before any global write.
// ---------------------------------------------------------------------------
__global__ __launch_bounds__(256) void att_kernel(
    const float* __restrict__ ctx, const float* __restrict__ q,
    float* __restrict__ att)
{
    const int bh = blockIdx.y;
    const int l0 = blockIdx.x << 6;
    __shared__ float sC[64][68];   // sC[k][dv]
    __shared__ float sQ[64][68];   // sQ[k][l]
    const int tid = threadIdx.x;
    const int kr = tid >> 2, c16 = (tid & 3) << 4;
    {
        const float* cp = ctx + (size_t)bh * 4096 + kr * 64 + c16;
        const float* qp = q + ((size_t)bh * 64 + kr) * L_ + l0 + c16;
#pragma unroll
        for (int i = 0; i < 4; ++i) {
            *(float4*)&sC[kr][c16 + 4 * i] = *(const float4*)(cp + 4 * i);
            *(float4*)&sQ[kr][c16 + 4 * i] = *(const float4*)(qp + 4 * i);
        }
    }
    __syncthreads();
    const int tx = tid & 15, ty = tid >> 4;
    float acc[4][4] = {};
#pragma unroll 8
    for (int k = 0; k < 64; ++k) {
        const float4 c4 = *(const float4*)&sC[k][ty << 2];
        const float4 q4 = *(const float4*)&sQ[k][tx << 2];
        const float a[4]  = {c4.x, c4.y, c4.z, c4.w};
        const float bb[4] = {q4.x, q4.y, q4.z, q4.w};
#pragma unroll
        for (int i = 0; i < 4; ++i)
#pragma unroll
            for (int j = 0; j < 4; ++j)
                acc[i][j] = fmaf(a[i], bb[j], acc[i][j]);
    }
#pragma unroll
    for (int i = 0; i < 4; ++i) {
        const size_t base = ((size_t)bh * 64 + (ty << 2) + i) * L_ + l0 + (tx << 2);
        float4 o4 = {acc[i][0], acc[i][1], acc[i][2], acc[i][3]};
        *(float4*)(att + base) = o4;
    }
}

// ---------------------------------------------------------------------------
// LayerNorm over channels (C_=512) for each (b,l); channels-first layout.
// ---------------------------------------------------------------------------
__global__ __launch_bounds__(256) void ln_kernel(
    const float* __restrict__ z, const float* __restrict__ g,
    const float* __restrict__ be, float* __restrict__ out)
{
    const int l = blockIdx.x * 256 + threadIdx.x;
    const int b = blockIdx.y;
    const float* p = z + (size_t)b * C_ * L_ + l;
    float s = 0.f, s2 = 0.f;
#pragma unroll 8
    for (int c = 0; c < C_; ++c) {
        const float x = p[(size_t)c * L_];
        s += x; s2 = fmaf(x, x, s2);
    }
    const float mean = s * (1.f / C_);
    const float var  = s2 * (1.f / C_) - mean * mean;
    const float inv  = rsqrtf(var + 1e-5f);
    float* op = out + (size_t)b * C_ * L_ + l;
#pragma unroll 8
    for (int c = 0; c < C_; ++c) {
        op[(size_t)c * L_] = (p[(size_t)c * L_] - mean) * inv * g[c] + be[c];
    }
}

// ---------------------------------------------------------------------------
extern "C" void kernel_launch(void* const* d_in, const int* in_sizes, int n_in,
                              void* d_out, int out_size, void* d_ws, size_t ws_size,
                              hipStream_t stream)
{
    const float* z1  = (const float*)d_in[0];
    const float* z2  = (const float*)d_in[1];
    const float* Wq  = (const float*)d_in[2];
    const float* bq  = (const float*)d_in[3];
    const float* Wk  = (const float*)d_in[4];
    const float* bk  = (const float*)d_in[5];
    const float* Wv  = (const float*)d_in[6];
    const float* bv  = (const float*)d_in[7];
    const float* Wr  = (const float*)d_in[8];
    const float* br  = (const float*)d_in[9];
    const float* g1  = (const float*)d_in[10];
    const float* be1 = (const float*)d_in[11];
    const float* W1  = (const float*)d_in[12];
    const float* b1  = (const float*)d_in[13];
    const float* W2  = (const float*)d_in[14];
    const float* b2  = (const float*)d_in[15];
    const float* g2  = (const float*)d_in[16];
    const float* be2 = (const float*)d_in[17];
    float* out = (float*)d_out;

    // Workspace budget: q(64MB) + k(64MB) + h_chunk(16MB) + ctx(1MB) = 145MB.
    // d_out doubles as scratch: holds v until ctx_kernel, then x (LN1 output)
    // until the FFN consumes it; final LN2 overwrites it with the real output.
    const size_t SZ = (size_t)B_ * C_ * L_;     // 16.78M floats
    float* ws   = (float*)d_ws;
    float* q    = ws;                           // [B,512,L]
    float* k    = ws + SZ;                      // [B,512,L]
    float* hbuf = ws + 2 * SZ;                  // [1024, L] one-batch FFN hidden
    float* ctxb = ws + 2 * SZ + (size_t)C2_ * L_;  // [B,H,64,64]
    float* v    = out;                          // v lives in d_out (dead after ctx)
    // aliases (stream-ordered reuse):
    float* att  = q;                            // att computed in-place over q
    float* z    = k;                            // k dead after ctx_kernel
    float* x    = out;                          // v dead after ctx_kernel
    float* y    = q;                            // att dead after Wr conv... see below

    const dim3 blk(256);
    // projections
    conv1x1_kernel<0,false><<<dim3(L_/64, C_/64, B_), blk, 0, stream>>>(Wq, z1, bq, nullptr, q, C_, C_);
    conv1x1_kernel<0,false><<<dim3(L_/64, C_/64, B_), blk, 0, stream>>>(Wk, z2, bk, nullptr, k, C_, C_);
    conv1x1_kernel<0,false><<<dim3(L_/64, C_/64, B_), blk, 0, stream>>>(Wv, z2, bv, nullptr, v, C_, C_);
    // softmaxes (in place)
    softmax_l_kernel<<<dim3(B_ * C_), blk, 0, stream>>>(k);
    softmax_c_kernel<<<dim3(L_/256, B_ * H_), blk, 0, stream>>>(q);
    // ctx = kh @ vh^T  (atomic-accumulated over 8 L-splits)
    zero_kernel<<<dim3((B_ * H_ * 64 * 64 / 4 + 255) / 256), blk, 0, stream>>>(ctxb, B_ * H_ * 64 * 64 / 4);
    ctx_kernel<<<dim3(8, B_ * H_), blk, 0, stream>>>(k, v, ctxb);
    // att = ctx^T @ qh   (in-place: att==q, per-block bijection staged via LDS)
    att_kernel<<<dim3(L_/64, B_ * H_), blk, 0, stream>>>(ctxb, q, att);
    // z = Wr @ att + br + z1   (z==k; k dead after ctx_kernel)
    conv1x1_kernel<0,true><<<dim3(L_/64, C_/64, B_), blk, 0, stream>>>(Wr, att, br, z1, z, C_, C_);
    // x = LN1(z)   (x==d_out; v dead after ctx_kernel)
    ln_kernel<<<dim3(L_/256, B_), blk, 0, stream>>>(z, g1, be1, x);
    // FFN per batch to keep h at 16MB: h_b = ELU(W1@x_b); y_b = W2@h_b
    // y==q (att dead after Wr conv).
    for (int b = 0; b < B_; ++b) {
        const float* xb = x + (size_t)b * C_ * L_;
        float*       yb = y + (size_t)b * C_ * L_;
        conv1x1_kernel<1,false><<<dim3(L_/64, C2_/64, 1), blk, 0, stream>>>(W1, xb, b1, nullptr, hbuf, C2_, C_);
        conv1x1_kernel<0,false><<<dim3(L_/64, C_/64, 1), blk, 0, stream>>>(W2, hbuf, b2, nullptr, yb, C_, C2_);
    }
    // out = LN2(y)  (final write to d_out)
    ln_kernel<<<dim3(L_/256, B_), blk, 0, stream>>>(y, g2, be2, out);
}

// Round 3
// 750.539 us; speedup vs baseline: 2.9527x; 2.9527x over previous
//
#include <hip/hip_runtime.h>
#include <math.h>

#define B_   8
#define C_   512
#define L_   4096
#define H_   8
#define DK_  64
#define C2_  1024

typedef unsigned short ushort;
typedef short     bf16x8_t __attribute__((ext_vector_type(8)));
typedef float     f32x4_t  __attribute__((ext_vector_type(4)));
typedef unsigned short u16x8 __attribute__((ext_vector_type(8)));
typedef unsigned short u16x4 __attribute__((ext_vector_type(4)));

__device__ __forceinline__ float bf2f(ushort u) {
    unsigned int x = ((unsigned int)u) << 16;
    float f; __builtin_memcpy(&f, &x, 4); return f;
}
__device__ __forceinline__ ushort f2bf(float f) {
    unsigned int x; __builtin_memcpy(&x, &f, 4);
    x = (x + 0x7FFFu + ((x >> 16) & 1u)) >> 16;   // RNE
    return (ushort)x;
}

#define GLOAD_LDS16(gp, lp) \
    __builtin_amdgcn_global_load_lds((const __attribute__((address_space(1))) void*)(gp), \
                                     (__attribute__((address_space(3))) void*)(lp), 16, 0, 0)

// ---------------------------------------------------------------------------
// transpose_in: fp32 [B,C,L] -> bf16 [B*L, C].  grid (L/64, C/64, B), 256 thr
// ---------------------------------------------------------------------------
__global__ __launch_bounds__(256) void transpose_in(const float* __restrict__ in,
                                                    ushort* __restrict__ out)
{
    const int b = blockIdx.z, c0 = blockIdx.y * 64, l0 = blockIdx.x * 64;
    __shared__ float t[64][65];
    const int tid = threadIdx.x;
    {
        const int c = tid >> 4, l4 = (tid & 15) * 4;
        const float* ip = in + ((size_t)b * C_ + c0) * L_ + l0;
#pragma unroll
        for (int cc = c; cc < 64; cc += 16) {
            float4 v = *(const float4*)(ip + (size_t)cc * L_ + l4);
            t[l4 + 0][cc] = v.x; t[l4 + 1][cc] = v.y;
            t[l4 + 2][cc] = v.z; t[l4 + 3][cc] = v.w;
        }
    }
    __syncthreads();
    {
        const int l = tid >> 3, c8 = (tid & 7) * 8;
        ushort* op = out + ((size_t)b * L_ + l0) * C_ + c0;
#pragma unroll
        for (int ll = l; ll < 64; ll += 32) {
            u16x8 v;
#pragma unroll
            for (int i = 0; i < 8; ++i) v[i] = f2bf(t[ll][c8 + i]);
            *(u16x8*)(op + (size_t)ll * C_ + c8) = v;
        }
    }
}

// ---------------------------------------------------------------------------
// transpose_out: fp32 [B*L, C] -> fp32 [B,C,L].  grid (L/64, C/64, B)
// ---------------------------------------------------------------------------
__global__ __launch_bounds__(256) void transpose_out(const float* __restrict__ in,
                                                     float* __restrict__ out)
{
    const int b = blockIdx.z, c0 = blockIdx.y * 64, l0 = blockIdx.x * 64;
    __shared__ float t[64][65];   // t[c][l]
    const int tid = threadIdx.x;
    {
        const int l = tid >> 4, c4 = (tid & 15) * 4;
#pragma unroll
        for (int ll = l; ll < 64; ll += 16) {
            float4 v = *(const float4*)(in + ((size_t)(b * L_ + l0 + ll)) * C_ + c0 + c4);
            t[c4 + 0][ll] = v.x; t[c4 + 1][ll] = v.y;
            t[c4 + 2][ll] = v.z; t[c4 + 3][ll] = v.w;
        }
    }
    __syncthreads();
    {
        const int c = tid >> 4, l4 = (tid & 15) * 4;
        float* op = out + ((size_t)b * C_ + c0) * L_ + l0;
#pragma unroll
        for (int cc = c; cc < 64; cc += 16) {
            float4 v = {t[cc][l4], t[cc][l4 + 1], t[cc][l4 + 2], t[cc][l4 + 3]};
            *(float4*)(op + (size_t)cc * L_ + l4) = v;
        }
    }
}

// ---------------------------------------------------------------------------
// cvt_bf16: fp32 -> bf16, n divisible by 4
// ---------------------------------------------------------------------------
__global__ __launch_bounds__(256) void cvt_bf16(const float* __restrict__ in,
                                                ushort* __restrict__ out, int n4)
{
    const int i = blockIdx.x * 256 + threadIdx.x;
    if (i < n4) {
        float4 v = *(const float4*)(in + 4 * (size_t)i);
        u16x4 o; o[0] = f2bf(v.x); o[1] = f2bf(v.y); o[2] = f2bf(v.z); o[3] = f2bf(v.w);
        *(u16x4*)(out + 4 * (size_t)i) = o;
    }
}

__global__ __launch_bounds__(256) void zero_kernel(float* __restrict__ p, int n4)
{
    const int i = blockIdx.x * 256 + threadIdx.x;
    if (i < n4) { float4 z = {0.f, 0.f, 0.f, 0.f}; *(float4*)(p + 4 * (size_t)i) = z; }
}

// ---------------------------------------------------------------------------
// conv_mfma: out[m,n] = act( sum_k A[m,k]*W[n,k] + bias[n] (+res[m,n]) )
// A: [M,K] bf16 (k-contig), W: [N,K] bf16 (k-contig), out: [M,N] bf16.
// Tile 128(m) x 128(n), BK=32, 256 threads (4 waves), mfma_f32_16x16x32_bf16.
// Staging: global_load_lds width 16, XOR k-slot swizzle (<=2-way LDS aliasing).
// ---------------------------------------------------------------------------
template<int ACT, bool HAS_RES>
__global__ __launch_bounds__(256) void conv_mfma(
    const ushort* __restrict__ A, const ushort* __restrict__ Wt,
    const float* __restrict__ bias, const ushort* __restrict__ res,
    ushort* __restrict__ out, int M, int N, int K)
{
    const int m0 = blockIdx.x * 128;
    const int n0 = blockIdx.y * 128;
    const int tid = threadIdx.x;
    const int w = tid >> 6, lane = tid & 63;
    const int wm = (w & 1) * 64, wn = (w >> 1) * 64;
    const int l16 = lane & 15, quad = lane >> 4;

    __shared__ ushort sA[128 * 32];   // [row][k] 64B rows, k-slot swizzled
    __shared__ ushort sB[128 * 32];

    f32x4_t acc[4][4];
#pragma unroll
    for (int i = 0; i < 4; ++i)
#pragma unroll
        for (int j = 0; j < 4; ++j) acc[i][j] = (f32x4_t){0.f, 0.f, 0.f, 0.f};

    const int srow = lane >> 2;       // 0..15
    const int sslot = lane & 3;       // physical 16B slot

    for (int c0 = 0; c0 < K; c0 += 32) {
        __syncthreads();
#pragma unroll
        for (int r = 0; r < 2; ++r) {
            const int row = r * 64 + w * 16 + srow;
            const int lk = sslot ^ ((row >> 2) & 3);   // logical k-part loaded into phys slot
            const ushort* ga = A  + (size_t)(m0 + row) * K + c0 + lk * 8;
            const ushort* gb = Wt + (size_t)(n0 + row) * K + c0 + lk * 8;
            ushort* la = sA + (r * 64 + w * 16) * 32;  // wave-uniform base
            ushort* lb = sB + (r * 64 + w * 16) * 32;
            GLOAD_LDS16(ga, la);
            GLOAD_LDS16(gb, lb);
        }
        __syncthreads();

        bf16x8_t af[4], bf[4];
#pragma unroll
        for (int i = 0; i < 4; ++i) {
            const int arow = wm + i * 16 + l16;
            const int ap = quad ^ ((arow >> 2) & 3);
            af[i] = *(const bf16x8_t*)(sA + arow * 32 + ap * 8);
            const int brow = wn + i * 16 + l16;
            const int bp = quad ^ ((brow >> 2) & 3);
            bf[i] = *(const bf16x8_t*)(sB + brow * 32 + bp * 8);
        }
#pragma unroll
        for (int i = 0; i < 4; ++i)
#pragma unroll
            for (int j = 0; j < 4; ++j)
                acc[i][j] = __builtin_amdgcn_mfma_f32_16x16x32_bf16(af[i], bf[j], acc[i][j], 0, 0, 0);
    }

    // epilogue: D row (m) = quad*4+reg, col (n) = lane&15
#pragma unroll
    for (int j = 0; j < 4; ++j) {
        const int o = n0 + wn + j * 16 + l16;
        const float bo = bias[o];
#pragma unroll
        for (int i = 0; i < 4; ++i) {
            const int mb = m0 + wm + i * 16 + quad * 4;
#pragma unroll
            for (int r = 0; r < 4; ++r) {
                float t = acc[i][j][r] + bo;
                const size_t idx = (size_t)(mb + r) * N + o;
                if (HAS_RES) t += bf2f(res[idx]);
                if (ACT == 1) t = (t > 0.f) ? t : (__expf(t) - 1.f);  // ELU
                out[idx] = f2bf(t);
            }
        }
    }
}

// ---------------------------------------------------------------------------
// softmax over L at fixed (b,c).  k: [B*L, C] bf16.  grid (C/32, B), 256 thr
// thread: column c = c0 + (tid&31), l-part = tid>>5 (8 parts x 512)
// ---------------------------------------------------------------------------
__global__ __launch_bounds__(256) void softmax_len(ushort* __restrict__ k)
{
    const int tid = threadIdx.x;
    const int c = tid & 31, part = tid >> 5;
    const int c0 = blockIdx.x * 32, b = blockIdx.y;
    ushort* base = k + (size_t)b * L_ * C_ + c0 + c;
    __shared__ float red[8][33];

    float m = -3.0e38f;
    for (int l = part * 512; l < part * 512 + 512; ++l)
        m = fmaxf(m, bf2f(base[(size_t)l * C_]));
    red[part][c] = m;
    __syncthreads();
#pragma unroll
    for (int p = 0; p < 8; ++p) m = fmaxf(m, red[p][c]);
    __syncthreads();

    float s = 0.f;
    for (int l = part * 512; l < part * 512 + 512; ++l)
        s += __expf(bf2f(base[(size_t)l * C_]) - m);
    red[part][c] = s;
    __syncthreads();
    s = 0.f;
#pragma unroll
    for (int p = 0; p < 8; ++p) s += red[p][c];
    const float inv = 1.f / s;

    for (int l = part * 512; l < part * 512 + 512; ++l) {
        ushort* p = base + (size_t)l * C_;
        *p = f2bf(__expf(bf2f(*p) - m) * inv);
    }
}

// ---------------------------------------------------------------------------
// softmax over 64 contiguous channels per head. q: [B*L, C] bf16. wave/row.
// ---------------------------------------------------------------------------
__global__ __launch_bounds__(256) void softmax_head(ushort* __restrict__ q)
{
    const int tid = threadIdx.x, w = tid >> 6, lane = tid & 63;
    const size_t row = (size_t)blockIdx.x * 4 + w;
    ushort* p = q + row * C_ + lane * 8;
    u16x8 v = *(const u16x8*)p;
    float f[8], m = -3.0e38f;
#pragma unroll
    for (int i = 0; i < 8; ++i) { f[i] = bf2f(v[i]); m = fmaxf(m, f[i]); }
    // reduce within 8-lane group (one head = 8 lanes * 8 ch)
    m = fmaxf(m, __shfl_xor(m, 1));
    m = fmaxf(m, __shfl_xor(m, 2));
    m = fmaxf(m, __shfl_xor(m, 4));
    float s = 0.f;
#pragma unroll
    for (int i = 0; i < 8; ++i) { f[i] = __expf(f[i] - m); s += f[i]; }
    s += __shfl_xor(s, 1); s += __shfl_xor(s, 2); s += __shfl_xor(s, 4);
    const float inv = 1.f / s;
#pragma unroll
    for (int i = 0; i < 8; ++i) v[i] = f2bf(f[i] * inv);
    *(u16x8*)p = v;
}

// ---------------------------------------------------------------------------
// ctxT[bh][dv][dk] += sum_l v[b,l,h*64+dv] * k[b,l,h*64+dk]   (fp32 atomics)
// grid (8 l-splits, B*H), 256 thr, acc 4x4/thread.
// ---------------------------------------------------------------------------
__global__ __launch_bounds__(256) void ctx_accum(
    const ushort* __restrict__ kk, const ushort* __restrict__ vv,
    float* __restrict__ ctx)
{
    const int bh = blockIdx.y, b = bh >> 3, h = bh & 7;
    const int l0 = blockIdx.x * 512;
    const int tid = threadIdx.x;
    __shared__ float sK[32][72];
    __shared__ float sV[32][72];
    const int srow = tid >> 3, c8 = (tid & 7) * 8;
    const int dv4 = (tid & 15) * 4, dk4 = (tid >> 4) * 4;
    float acc[4][4] = {};

    for (int lt = 0; lt < 512; lt += 32) {
        const size_t gbase = ((size_t)(b * L_ + l0 + lt + srow)) * C_ + h * 64 + c8;
        u16x8 kv = *(const u16x8*)(kk + gbase);
        u16x8 vvv = *(const u16x8*)(vv + gbase);
        __syncthreads();
#pragma unroll
        for (int i = 0; i < 8; ++i) { sK[srow][c8 + i] = bf2f(kv[i]); sV[srow][c8 + i] = bf2f(vvv[i]); }
        __syncthreads();
#pragma unroll
        for (int ll = 0; ll < 32; ++ll) {
            const float4 a = *(const float4*)&sV[ll][dv4];
            const float4 bb = *(const float4*)&sK[ll][dk4];
            const float av[4] = {a.x, a.y, a.z, a.w};
            const float bv[4] = {bb.x, bb.y, bb.z, bb.w};
#pragma unroll
            for (int i = 0; i < 4; ++i)
#pragma unroll
                for (int j = 0; j < 4; ++j)
                    acc[i][j] = fmaf(av[i], bv[j], acc[i][j]);
        }
    }
    float* cp = ctx + (size_t)bh * 4096;
#pragma unroll
    for (int i = 0; i < 4; ++i)
#pragma unroll
        for (int j = 0; j < 4; ++j)
            atomicAdd(&cp[(dv4 + i) * 64 + (dk4 + j)], acc[i][j]);
}

// ---------------------------------------------------------------------------
// att[b,l,h*64+dv] = sum_dk q[b,l,h*64+dk] * ctxT[bh][dv][dk]   (MFMA)
// grid (L/128, B*H), 256 thr.
// ---------------------------------------------------------------------------
__global__ __launch_bounds__(256) void att_mfma(
    const ushort* __restrict__ q, const float* __restrict__ ctx,
    ushort* __restrict__ att)
{
    const int bh = blockIdx.y, b = bh >> 3, h = bh & 7;
    const int l0 = blockIdx.x * 128;
    const int tid = threadIdx.x, w = tid >> 6, lane = tid & 63;
    const int l16 = lane & 15, quad = lane >> 4;

    __shared__ ushort sQ[128 * 72];   // [l][dk], padded rows (144B)
    __shared__ ushort sC[64 * 72];    // [dv][dk], padded rows

    {
        const int part = tid & 7;
        for (int rr = tid >> 3; rr < 128; rr += 32) {
            u16x8 v = *(const u16x8*)(q + ((size_t)(b * L_ + l0 + rr)) * C_ + h * 64 + part * 8);
            *(u16x8*)(sQ + rr * 72 + part * 8) = v;
        }
        const int dv = tid >> 2, dk0 = (tid & 3) * 16;
        const float* cp = ctx + (size_t)bh * 4096 + dv * 64 + dk0;
#pragma unroll
        for (int i = 0; i < 16; ++i) sC[dv * 72 + dk0 + i] = f2bf(cp[i]);
    }
    __syncthreads();

    f32x4_t acc[2][4];
#pragma unroll
    for (int i = 0; i < 2; ++i)
#pragma unroll
        for (int j = 0; j < 4; ++j) acc[i][j] = (f32x4_t){0.f, 0.f, 0.f, 0.f};

#pragma unroll
    for (int ks = 0; ks < 2; ++ks) {
        const int k0 = ks * 32;
        bf16x8_t aq[2], bc[4];
#pragma unroll
        for (int i = 0; i < 2; ++i)
            aq[i] = *(const bf16x8_t*)(sQ + (w * 32 + i * 16 + l16) * 72 + k0 + quad * 8);
#pragma unroll
        for (int j = 0; j < 4; ++j)
            bc[j] = *(const bf16x8_t*)(sC + (j * 16 + l16) * 72 + k0 + quad * 8);
#pragma unroll
        for (int i = 0; i < 2; ++i)
#pragma unroll
            for (int j = 0; j < 4; ++j)
                acc[i][j] = __builtin_amdgcn_mfma_f32_16x16x32_bf16(aq[i], bc[j], acc[i][j], 0, 0, 0);
    }

#pragma unroll
    for (int j = 0; j < 4; ++j)
#pragma unroll
        for (int i = 0; i < 2; ++i) {
            const int mb = l0 + w * 32 + i * 16 + quad * 4;
#pragma unroll
            for (int r = 0; r < 4; ++r)
                att[((size_t)(b * L_ + mb + r)) * C_ + h * 64 + j * 16 + l16] = f2bf(acc[i][j][r]);
        }
}

// ---------------------------------------------------------------------------
// LayerNorm over 512 contiguous channels; wave per row; bf16 in, bf16/f32 out
// ---------------------------------------------------------------------------
template<bool OUTF32>
__global__ __launch_bounds__(256) void ln_row(
    const ushort* __restrict__ in, const float* __restrict__ g,
    const float* __restrict__ be, ushort* __restrict__ outb,
    float* __restrict__ outf)
{
    const int tid = threadIdx.x, w = tid >> 6, lane = tid & 63;
    const size_t row = (size_t)blockIdx.x * 4 + w;
    const ushort* p = in + row * C_ + lane * 8;
    u16x8 v = *(const u16x8*)p;
    float f[8], s = 0.f, s2 = 0.f;
#pragma unroll
    for (int i = 0; i < 8; ++i) { f[i] = bf2f(v[i]); s += f[i]; s2 = fmaf(f[i], f[i], s2); }
#pragma unroll
    for (int o = 1; o < 64; o <<= 1) { s += __shfl_xor(s, o); s2 += __shfl_xor(s2, o); }
    const float mean = s * (1.f / C_);
    const float var  = s2 * (1.f / C_) - mean * mean;
    const float inv  = rsqrtf(var + 1e-5f);
    if (OUTF32) {
        float* op = outf + row * C_ + lane * 8;
#pragma unroll
        for (int i = 0; i < 8; ++i)
            op[i] = (f[i] - mean) * inv * g[lane * 8 + i] + be[lane * 8 + i];
    } else {
        u16x8 ov;
#pragma unroll
        for (int i = 0; i < 8; ++i)
            ov[i] = f2bf((f[i] - mean) * inv * g[lane * 8 + i] + be[lane * 8 + i]);
        *(u16x8*)(outb + row * C_ + lane * 8) = ov;
    }
}

// ---------------------------------------------------------------------------
extern "C" void kernel_launch(void* const* d_in, const int* in_sizes, int n_in,
                              void* d_out, int out_size, void* d_ws, size_t ws_size,
                              hipStream_t stream)
{
    const float* z1  = (const float*)d_in[0];
    const float* z2  = (const float*)d_in[1];
    const float* Wq  = (const float*)d_in[2];
    const float* bq  = (const float*)d_in[3];
    const float* Wk  = (const float*)d_in[4];
    const float* bk  = (const float*)d_in[5];
    const float* Wv  = (const float*)d_in[6];
    const float* bv  = (const float*)d_in[7];
    const float* Wr  = (const float*)d_in[8];
    const float* br  = (const float*)d_in[9];
    const float* g1  = (const float*)d_in[10];
    const float* be1 = (const float*)d_in[11];
    const float* W1  = (const float*)d_in[12];
    const float* b1  = (const float*)d_in[13];
    const float* W2  = (const float*)d_in[14];
    const float* b2  = (const float*)d_in[15];
    const float* g2  = (const float*)d_in[16];
    const float* be2 = (const float*)d_in[17];
    float* out = (float*)d_out;

    const size_t SB = (size_t)B_ * L_ * C_;     // 16.78M bf16 elems per buffer
    ushort* ws16 = (ushort*)d_ws;
    ushort* b0v = ws16;            // z1t -> y
    ushort* b1v = ws16 + SB;       // z2t -> att
    ushort* b2v = ws16 + 2 * SB;   // q   -> z    -> yf32(lo)
    ushort* b3v = ws16 + 3 * SB;   // k   -> x    -> yf32(hi)
    ushort* wb  = ws16 + 4 * SB;   // bf16 weights (4MB)
    ushort* wbq = wb;
    ushort* wbk = wb + 262144;
    ushort* wbv = wb + 524288;
    ushort* wbr = wb + 786432;
    ushort* wb1 = wb + 1048576;
    ushort* wb2 = wb + 1572864;
    float*  ctxf = (float*)(wb + 2097152);       // [B*H,64,64] fp32, 1MB
    ushort* vbuf = (ushort*)d_out;               // v lives in d_out (33.5MB)
    ushort* hbuf = (ushort*)d_out;               // h: [B*L, 1024] bf16 (67MB)
    float*  yf32 = (float*)b2v;                  // spans b2v+b3v (67MB)

    const dim3 blk(256);
    const int M = B_ * L_;   // 32768

    // 0) input transposes + weight casts
    transpose_in<<<dim3(L_/64, C_/64, B_), blk, 0, stream>>>(z1, b0v);
    transpose_in<<<dim3(L_/64, C_/64, B_), blk, 0, stream>>>(z2, b1v);
    cvt_bf16<<<dim3(262144/4/256), blk, 0, stream>>>(Wq, wbq, 262144/4);
    cvt_bf16<<<dim3(262144/4/256), blk, 0, stream>>>(Wk, wbk, 262144/4);
    cvt_bf16<<<dim3(262144/4/256), blk, 0, stream>>>(Wv, wbv, 262144/4);
    cvt_bf16<<<dim3(262144/4/256), blk, 0, stream>>>(Wr, wbr, 262144/4);
    cvt_bf16<<<dim3(524288/4/256), blk, 0, stream>>>(W1, wb1, 524288/4);
    cvt_bf16<<<dim3(524288/4/256), blk, 0, stream>>>(W2, wb2, 524288/4);

    // 1) projections (MFMA)
    conv_mfma<0,false><<<dim3(M/128, C_/128), blk, 0, stream>>>(b0v, wbq, bq, nullptr, b2v, M, C_, C_);
    conv_mfma<0,false><<<dim3(M/128, C_/128), blk, 0, stream>>>(b1v, wbk, bk, nullptr, b3v, M, C_, C_);
    conv_mfma<0,false><<<dim3(M/128, C_/128), blk, 0, stream>>>(b1v, wbv, bv, nullptr, vbuf, M, C_, C_);

    // 2) softmaxes
    softmax_len<<<dim3(C_/32, B_), blk, 0, stream>>>(b3v);
    softmax_head<<<dim3(M/4), blk, 0, stream>>>(b2v);

    // 3) ctxT = V^T K  (fp32 atomics over 8 l-splits)
    zero_kernel<<<dim3(65536/256), blk, 0, stream>>>(ctxf, 65536);
    ctx_accum<<<dim3(8, B_ * H_), blk, 0, stream>>>(b3v, vbuf, ctxf);

    // 4) att = q . ctxT^T per head (MFMA); att -> b1v (z2t dead)
    att_mfma<<<dim3(L_/128, B_ * H_), blk, 0, stream>>>(b2v, ctxf, b1v);

    // 5) z = Wr@att + br + z1t  -> b2v (q dead)
    conv_mfma<0,true><<<dim3(M/128, C_/128), blk, 0, stream>>>(b1v, wbr, br, b0v, b2v, M, C_, C_);

    // 6) x = LN1(z) -> b3v (k dead)
    ln_row<false><<<dim3(M/4), blk, 0, stream>>>(b2v, g1, be1, b3v, nullptr);

    // 7) h = ELU(W1@x) -> d_out (v dead)
    conv_mfma<1,false><<<dim3(M/128, C2_/128), blk, 0, stream>>>(b3v, wb1, b1, nullptr, hbuf, M, C2_, C_);

    // 8) y = W2@h -> b0v (z1t dead)
    conv_mfma<0,false><<<dim3(M/128, C_/128), blk, 0, stream>>>(hbuf, wb2, b2, nullptr, b0v, M, C_, C2_);

    // 9) LN2 -> fp32 [B*L,C] into b2v+b3v region (z,x dead)
    ln_row<true><<<dim3(M/4), blk, 0, stream>>>(b0v, g2, be2, nullptr, yf32);

    // 10) transpose to [B,C,L] fp32 -> d_out (h dead)
    transpose_out<<<dim3(L_/64, C_/64, B_), blk, 0, stream>>>(yf32, out);
}

// Round 4
// 601.242 us; speedup vs baseline: 3.6859x; 1.2483x over previous
//
#include <hip/hip_runtime.h>
#include <math.h>

#define B_   8
#define C_   512
#define L_   4096
#define H_   8
#define DK_  64
#define C2_  1024

typedef unsigned short ushort;
typedef short     bf16x8_t __attribute__((ext_vector_type(8)));
typedef float     f32x4_t  __attribute__((ext_vector_type(4)));
typedef unsigned short u16x8 __attribute__((ext_vector_type(8)));
typedef unsigned short u16x4 __attribute__((ext_vector_type(4)));

__device__ __forceinline__ float bf2f(ushort u) {
    unsigned int x = ((unsigned int)u) << 16;
    float f; __builtin_memcpy(&f, &x, 4); return f;
}
__device__ __forceinline__ ushort f2bf(float f) {
    unsigned int x; __builtin_memcpy(&x, &f, 4);
    x = (x + 0x7FFFu + ((x >> 16) & 1u)) >> 16;   // RNE
    return (ushort)x;
}

#define GLOAD_LDS16(gp, lp) \
    __builtin_amdgcn_global_load_lds((const __attribute__((address_space(1))) void*)(gp), \
                                     (__attribute__((address_space(3))) void*)(lp), 16, 0, 0)

// ---------------------------------------------------------------------------
// transpose_in: fp32 [B,C,L] -> bf16 [B*L, C].  grid (L/64, C/64, B), 256 thr
// ---------------------------------------------------------------------------
__global__ __launch_bounds__(256) void transpose_in(const float* __restrict__ in,
                                                    ushort* __restrict__ out)
{
    const int b = blockIdx.z, c0 = blockIdx.y * 64, l0 = blockIdx.x * 64;
    __shared__ float t[64][65];
    const int tid = threadIdx.x;
    {
        const int c = tid >> 4, l4 = (tid & 15) * 4;
        const float* ip = in + ((size_t)b * C_ + c0) * L_ + l0;
#pragma unroll
        for (int cc = c; cc < 64; cc += 16) {
            float4 v = *(const float4*)(ip + (size_t)cc * L_ + l4);
            t[l4 + 0][cc] = v.x; t[l4 + 1][cc] = v.y;
            t[l4 + 2][cc] = v.z; t[l4 + 3][cc] = v.w;
        }
    }
    __syncthreads();
    {
        const int l = tid >> 3, c8 = (tid & 7) * 8;
        ushort* op = out + ((size_t)b * L_ + l0) * C_ + c0;
#pragma unroll
        for (int ll = l; ll < 64; ll += 32) {
            u16x8 v;
#pragma unroll
            for (int i = 0; i < 8; ++i) v[i] = f2bf(t[ll][c8 + i]);
            *(u16x8*)(op + (size_t)ll * C_ + c8) = v;
        }
    }
}

// ---------------------------------------------------------------------------
// transpose_out: fp32 [B*L, C] -> fp32 [B,C,L].  grid (L/64, C/64, B)
// ---------------------------------------------------------------------------
__global__ __launch_bounds__(256) void transpose_out(const float* __restrict__ in,
                                                     float* __restrict__ out)
{
    const int b = blockIdx.z, c0 = blockIdx.y * 64, l0 = blockIdx.x * 64;
    __shared__ float t[64][65];   // t[c][l]
    const int tid = threadIdx.x;
    {
        const int l = tid >> 4, c4 = (tid & 15) * 4;
#pragma unroll
        for (int ll = l; ll < 64; ll += 16) {
            float4 v = *(const float4*)(in + ((size_t)(b * L_ + l0 + ll)) * C_ + c0 + c4);
            t[c4 + 0][ll] = v.x; t[c4 + 1][ll] = v.y;
            t[c4 + 2][ll] = v.z; t[c4 + 3][ll] = v.w;
        }
    }
    __syncthreads();
    {
        const int c = tid >> 4, l4 = (tid & 15) * 4;
        float* op = out + ((size_t)b * C_ + c0) * L_ + l0;
#pragma unroll
        for (int cc = c; cc < 64; cc += 16) {
            float4 v = {t[cc][l4], t[cc][l4 + 1], t[cc][l4 + 2], t[cc][l4 + 3]};
            *(float4*)(op + (size_t)cc * L_ + l4) = v;
        }
    }
}

__global__ __launch_bounds__(256) void cvt_bf16(const float* __restrict__ in,
                                                ushort* __restrict__ out, int n4)
{
    const int i = blockIdx.x * 256 + threadIdx.x;
    if (i < n4) {
        float4 v = *(const float4*)(in + 4 * (size_t)i);
        u16x4 o; o[0] = f2bf(v.x); o[1] = f2bf(v.y); o[2] = f2bf(v.z); o[3] = f2bf(v.w);
        *(u16x4*)(out + 4 * (size_t)i) = o;
    }
}

__global__ __launch_bounds__(256) void zero_kernel(float* __restrict__ p, int n4)
{
    const int i = blockIdx.x * 256 + threadIdx.x;
    if (i < n4) { float4 z = {0.f, 0.f, 0.f, 0.f}; *(float4*)(p + 4 * (size_t)i) = z; }
}

// ---------------------------------------------------------------------------
// conv_mfma: out[m,n] = act( sum_k A[m,k]*W[n,k] + bias[n] (+res[m,n]) )
// ---------------------------------------------------------------------------
template<int ACT, bool HAS_RES>
__global__ __launch_bounds__(256) void conv_mfma(
    const ushort* __restrict__ A, const ushort* __restrict__ Wt,
    const float* __restrict__ bias, const ushort* __restrict__ res,
    ushort* __restrict__ out, int M, int N, int K)
{
    const int m0 = blockIdx.x * 128;
    const int n0 = blockIdx.y * 128;
    const int tid = threadIdx.x;
    const int w = tid >> 6, lane = tid & 63;
    const int wm = (w & 1) * 64, wn = (w >> 1) * 64;
    const int l16 = lane & 15, quad = lane >> 4;

    __shared__ ushort sA[128 * 32];   // [row][k] 64B rows, k-slot swizzled
    __shared__ ushort sB[128 * 32];

    f32x4_t acc[4][4];
#pragma unroll
    for (int i = 0; i < 4; ++i)
#pragma unroll
        for (int j = 0; j < 4; ++j) acc[i][j] = (f32x4_t){0.f, 0.f, 0.f, 0.f};

    const int srow = lane >> 2;       // 0..15
    const int sslot = lane & 3;       // physical 16B slot

    for (int c0 = 0; c0 < K; c0 += 32) {
        __syncthreads();
#pragma unroll
        for (int r = 0; r < 2; ++r) {
            const int row = r * 64 + w * 16 + srow;
            const int lk = sslot ^ ((row >> 2) & 3);
            const ushort* ga = A  + (size_t)(m0 + row) * K + c0 + lk * 8;
            const ushort* gb = Wt + (size_t)(n0 + row) * K + c0 + lk * 8;
            ushort* la = sA + (r * 64 + w * 16) * 32;
            ushort* lb = sB + (r * 64 + w * 16) * 32;
            GLOAD_LDS16(ga, la);
            GLOAD_LDS16(gb, lb);
        }
        __syncthreads();

        bf16x8_t af[4], bf[4];
#pragma unroll
        for (int i = 0; i < 4; ++i) {
            const int arow = wm + i * 16 + l16;
            const int ap = quad ^ ((arow >> 2) & 3);
            af[i] = *(const bf16x8_t*)(sA + arow * 32 + ap * 8);
            const int brow = wn + i * 16 + l16;
            const int bp = quad ^ ((brow >> 2) & 3);
            bf[i] = *(const bf16x8_t*)(sB + brow * 32 + bp * 8);
        }
#pragma unroll
        for (int i = 0; i < 4; ++i)
#pragma unroll
            for (int j = 0; j < 4; ++j)
                acc[i][j] = __builtin_amdgcn_mfma_f32_16x16x32_bf16(af[i], bf[j], acc[i][j], 0, 0, 0);
    }

#pragma unroll
    for (int j = 0; j < 4; ++j) {
        const int o = n0 + wn + j * 16 + l16;
        const float bo = bias[o];
#pragma unroll
        for (int i = 0; i < 4; ++i) {
            const int mb = m0 + wm + i * 16 + quad * 4;
#pragma unroll
            for (int r = 0; r < 4; ++r) {
                float t = acc[i][j][r] + bo;
                const size_t idx = (size_t)(mb + r) * N + o;
                if (HAS_RES) t += bf2f(res[idx]);
                if (ACT == 1) t = (t > 0.f) ? t : (__expf(t) - 1.f);  // ELU
                out[idx] = f2bf(t);
            }
        }
    }
}

// ---------------------------------------------------------------------------
// kstat_chunk: per-chunk column (max, expsum) of k [B*L, C] bf16.
// grid (C/64, B*8), 256 thr. Chunk = 512 rows. stats[b*C+c][ch] float2.
// ---------------------------------------------------------------------------
__global__ __launch_bounds__(256) void kstat_chunk(const ushort* __restrict__ k,
                                                   float2* __restrict__ stats)
{
    const int cg = blockIdx.x;            // col group (64 cols)
    const int bc = blockIdx.y;            // b*8 + ch
    const int b = bc >> 3, ch = bc & 7;
    const int tid = threadIdx.x;
    const int g = tid & 7;                // 8-col subgroup
    const int kk = tid >> 3;              // 0..31 row worker
    const int w = tid >> 6, lane = tid & 63;
    const ushort* base = k + ((size_t)(b * L_) + ch * 512) * C_ + cg * 64 + g * 8;

    __shared__ float red[4][8][8];
    __shared__ float mcol[64];

    float fm[8];
#pragma unroll
    for (int i = 0; i < 8; ++i) fm[i] = -3.0e38f;
    for (int r = kk; r < 512; r += 32) {
        u16x8 v = *(const u16x8*)(base + (size_t)r * C_);
#pragma unroll
        for (int i = 0; i < 8; ++i) fm[i] = fmaxf(fm[i], bf2f(v[i]));
    }
#pragma unroll
    for (int off = 8; off <= 32; off <<= 1)
#pragma unroll
        for (int i = 0; i < 8; ++i) fm[i] = fmaxf(fm[i], __shfl_xor(fm[i], off));
    if ((lane >> 3) == 0)
#pragma unroll
        for (int i = 0; i < 8; ++i) red[w][g][i] = fm[i];
    __syncthreads();
    if (tid < 64) {
        const int g2 = tid >> 3, j = tid & 7;
        mcol[g2 * 8 + j] = fmaxf(fmaxf(red[0][g2][j], red[1][g2][j]),
                                 fmaxf(red[2][g2][j], red[3][g2][j]));
    }
    __syncthreads();
    float fmc[8];
#pragma unroll
    for (int i = 0; i < 8; ++i) fmc[i] = mcol[g * 8 + i];

    float fs[8] = {};
    for (int r = kk; r < 512; r += 32) {
        u16x8 v = *(const u16x8*)(base + (size_t)r * C_);
#pragma unroll
        for (int i = 0; i < 8; ++i) fs[i] += __expf(bf2f(v[i]) - fmc[i]);
    }
#pragma unroll
    for (int off = 8; off <= 32; off <<= 1)
#pragma unroll
        for (int i = 0; i < 8; ++i) fs[i] += __shfl_xor(fs[i], off);
    __syncthreads();
    if ((lane >> 3) == 0)
#pragma unroll
        for (int i = 0; i < 8; ++i) red[w][g][i] = fs[i];
    __syncthreads();
    if (tid < 64) {
        const int g2 = tid >> 3, j = tid & 7;
        const float s = red[0][g2][j] + red[1][g2][j] + red[2][g2][j] + red[3][g2][j];
        const int c = cg * 64 + g2 * 8 + j;
        stats[((size_t)(b * C_ + c)) * 8 + ch] = make_float2(mcol[g2 * 8 + j], s);
    }
}

// ---------------------------------------------------------------------------
// kstat_merge: global (m, 1/S) per (b,c) from 8 chunk stats.
// ---------------------------------------------------------------------------
__global__ __launch_bounds__(256) void kstat_merge(const float2* __restrict__ stats,
                                                   float2* __restrict__ minv)
{
    const int i = blockIdx.x * 256 + threadIdx.x;
    if (i >= B_ * C_) return;
    float2 st[8];
    float m = -3.0e38f;
#pragma unroll
    for (int ch = 0; ch < 8; ++ch) { st[ch] = stats[(size_t)i * 8 + ch]; m = fmaxf(m, st[ch].x); }
    float s = 0.f;
#pragma unroll
    for (int ch = 0; ch < 8; ++ch) s += st[ch].y * __expf(st[ch].x - m);
    minv[i] = make_float2(m, 1.f / s);
}

// ---------------------------------------------------------------------------
// ctx_accum: ctxT[bh][dv][dk] += sum_l v[b,l,h*64+dv] * softmax_k[b,l,h*64+dk]
// k is RAW logits; softmax applied on the fly via minv. fp32 atomics.
// ---------------------------------------------------------------------------
__global__ __launch_bounds__(256) void ctx_accum(
    const ushort* __restrict__ kk, const ushort* __restrict__ vv,
    const float2* __restrict__ minv, float* __restrict__ ctx)
{
    const int bh = blockIdx.y, b = bh >> 3, h = bh & 7;
    const int l0 = blockIdx.x * 512;
    const int tid = threadIdx.x;
    __shared__ float sK[32][72];
    __shared__ float sV[32][72];
    const int srow = tid >> 3, c8 = (tid & 7) * 8;
    const int dv4 = (tid & 15) * 4, dk4 = (tid >> 4) * 4;

    float2 cst[8];
    {
        const float2* mp = minv + (size_t)b * C_ + h * 64 + c8;
#pragma unroll
        for (int i = 0; i < 8; ++i) cst[i] = mp[i];
    }
    float acc[4][4] = {};

    for (int lt = 0; lt < 512; lt += 32) {
        const size_t gbase = ((size_t)(b * L_ + l0 + lt + srow)) * C_ + h * 64 + c8;
        u16x8 kv = *(const u16x8*)(kk + gbase);
        u16x8 vvv = *(const u16x8*)(vv + gbase);
        __syncthreads();
#pragma unroll
        for (int i = 0; i < 8; ++i) {
            sK[srow][c8 + i] = __expf(bf2f(kv[i]) - cst[i].x) * cst[i].y;
            sV[srow][c8 + i] = bf2f(vvv[i]);
        }
        __syncthreads();
#pragma unroll
        for (int ll = 0; ll < 32; ++ll) {
            const float4 a = *(const float4*)&sV[ll][dv4];
            const float4 bb = *(const float4*)&sK[ll][dk4];
            const float av[4] = {a.x, a.y, a.z, a.w};
            const float bv[4] = {bb.x, bb.y, bb.z, bb.w};
#pragma unroll
            for (int i = 0; i < 4; ++i)
#pragma unroll
                for (int j = 0; j < 4; ++j)
                    acc[i][j] = fmaf(av[i], bv[j], acc[i][j]);
        }
    }
    float* cp = ctx + (size_t)bh * 4096;
#pragma unroll
    for (int i = 0; i < 4; ++i)
#pragma unroll
        for (int j = 0; j < 4; ++j)
            atomicAdd(&cp[(dv4 + i) * 64 + (dk4 + j)], acc[i][j]);
}

// ---------------------------------------------------------------------------
// att_mfma: att[b,l,h*64+dv] = sum_dk softmax_q[...dk] * ctxT[bh][dv][dk]
// q is RAW logits; per-row softmax over 64 dk fused into the staging loop
// (8 lanes/row shuffle-reduce). grid (L/128, B*H), 256 thr.
// ---------------------------------------------------------------------------
__global__ __launch_bounds__(256) void att_mfma(
    const ushort* __restrict__ q, const float* __restrict__ ctx,
    ushort* __restrict__ att)
{
    const int bh = blockIdx.y, b = bh >> 3, h = bh & 7;
    const int l0 = blockIdx.x * 128;
    const int tid = threadIdx.x, w = tid >> 6, lane = tid & 63;
    const int l16 = lane & 15, quad = lane >> 4;

    __shared__ ushort sQ[128 * 72];   // [l][dk]
    __shared__ ushort sC[64 * 72];    // [dv][dk]

    {
        const int part = tid & 7;
#pragma unroll
        for (int rr = tid >> 3; rr < 128; rr += 32) {
            u16x8 v = *(const u16x8*)(q + ((size_t)(b * L_ + l0 + rr)) * C_ + h * 64 + part * 8);
            float f[8], m = -3.0e38f;
#pragma unroll
            for (int i = 0; i < 8; ++i) { f[i] = bf2f(v[i]); m = fmaxf(m, f[i]); }
            m = fmaxf(m, __shfl_xor(m, 1));
            m = fmaxf(m, __shfl_xor(m, 2));
            m = fmaxf(m, __shfl_xor(m, 4));
            float s = 0.f;
#pragma unroll
            for (int i = 0; i < 8; ++i) { f[i] = __expf(f[i] - m); s += f[i]; }
            s += __shfl_xor(s, 1); s += __shfl_xor(s, 2); s += __shfl_xor(s, 4);
            const float inv = 1.f / s;
            u16x8 o;
#pragma unroll
            for (int i = 0; i < 8; ++i) o[i] = f2bf(f[i] * inv);
            *(u16x8*)(sQ + rr * 72 + part * 8) = o;
        }
        const int dv = tid >> 2, dk0 = (tid & 3) * 16;
        const float* cp = ctx + (size_t)bh * 4096 + dv * 64 + dk0;
#pragma unroll
        for (int i = 0; i < 16; ++i) sC[dv * 72 + dk0 + i] = f2bf(cp[i]);
    }
    __syncthreads();

    f32x4_t acc[2][4];
#pragma unroll
    for (int i = 0; i < 2; ++i)
#pragma unroll
        for (int j = 0; j < 4; ++j) acc[i][j] = (f32x4_t){0.f, 0.f, 0.f, 0.f};

#pragma unroll
    for (int ks = 0; ks < 2; ++ks) {
        const int k0 = ks * 32;
        bf16x8_t aq[2], bc[4];
#pragma unroll
        for (int i = 0; i < 2; ++i)
            aq[i] = *(const bf16x8_t*)(sQ + (w * 32 + i * 16 + l16) * 72 + k0 + quad * 8);
#pragma unroll
        for (int j = 0; j < 4; ++j)
            bc[j] = *(const bf16x8_t*)(sC + (j * 16 + l16) * 72 + k0 + quad * 8);
#pragma unroll
        for (int i = 0; i < 2; ++i)
#pragma unroll
            for (int j = 0; j < 4; ++j)
                acc[i][j] = __builtin_amdgcn_mfma_f32_16x16x32_bf16(aq[i], bc[j], acc[i][j], 0, 0, 0);
    }

#pragma unroll
    for (int j = 0; j < 4; ++j)
#pragma unroll
        for (int i = 0; i < 2; ++i) {
            const int mb = l0 + w * 32 + i * 16 + quad * 4;
#pragma unroll
            for (int r = 0; r < 4; ++r)
                att[((size_t)(b * L_ + mb + r)) * C_ + h * 64 + j * 16 + l16] = f2bf(acc[i][j][r]);
        }
}

// ---------------------------------------------------------------------------
// LayerNorm over 512 contiguous channels; wave per row.
// ---------------------------------------------------------------------------
template<bool OUTF32>
__global__ __launch_bounds__(256) void ln_row(
    const ushort* __restrict__ in, const float* __restrict__ g,
    const float* __restrict__ be, ushort* __restrict__ outb,
    float* __restrict__ outf)
{
    const int tid = threadIdx.x, w = tid >> 6, lane = tid & 63;
    const size_t row = (size_t)blockIdx.x * 4 + w;
    const ushort* p = in + row * C_ + lane * 8;
    u16x8 v = *(const u16x8*)p;
    float f[8], s = 0.f, s2 = 0.f;
#pragma unroll
    for (int i = 0; i < 8; ++i) { f[i] = bf2f(v[i]); s += f[i]; s2 = fmaf(f[i], f[i], s2); }
#pragma unroll
    for (int o = 1; o < 64; o <<= 1) { s += __shfl_xor(s, o); s2 += __shfl_xor(s2, o); }
    const float mean = s * (1.f / C_);
    const float var  = s2 * (1.f / C_) - mean * mean;
    const float inv  = rsqrtf(var + 1e-5f);
    if (OUTF32) {
        float* op = outf + row * C_ + lane * 8;
#pragma unroll
        for (int i = 0; i < 8; ++i)
            op[i] = (f[i] - mean) * inv * g[lane * 8 + i] + be[lane * 8 + i];
    } else {
        u16x8 ov;
#pragma unroll
        for (int i = 0; i < 8; ++i)
            ov[i] = f2bf((f[i] - mean) * inv * g[lane * 8 + i] + be[lane * 8 + i]);
        *(u16x8*)(outb + row * C_ + lane * 8) = ov;
    }
}

// ---------------------------------------------------------------------------
extern "C" void kernel_launch(void* const* d_in, const int* in_sizes, int n_in,
                              void* d_out, int out_size, void* d_ws, size_t ws_size,
                              hipStream_t stream)
{
    const float* z1  = (const float*)d_in[0];
    const float* z2  = (const float*)d_in[1];
    const float* Wq  = (const float*)d_in[2];
    const float* bq  = (const float*)d_in[3];
    const float* Wk  = (const float*)d_in[4];
    const float* bk  = (const float*)d_in[5];
    const float* Wv  = (const float*)d_in[6];
    const float* bv  = (const float*)d_in[7];
    const float* Wr  = (const float*)d_in[8];
    const float* br  = (const float*)d_in[9];
    const float* g1  = (const float*)d_in[10];
    const float* be1 = (const float*)d_in[11];
    const float* W1  = (const float*)d_in[12];
    const float* b1  = (const float*)d_in[13];
    const float* W2  = (const float*)d_in[14];
    const float* b2  = (const float*)d_in[15];
    const float* g2  = (const float*)d_in[16];
    const float* be2 = (const float*)d_in[17];
    float* out = (float*)d_out;

    const size_t SB = (size_t)B_ * L_ * C_;     // 16.78M elems per bf16 buffer
    ushort* ws16 = (ushort*)d_ws;
    ushort* b0v = ws16;            // z1t -> y
    ushort* b1v = ws16 + SB;       // z2t -> att
    ushort* b2v = ws16 + 2 * SB;   // q(raw) -> z -> yf32(lo)
    ushort* b3v = ws16 + 3 * SB;   // k(raw) -> x -> yf32(hi)
    ushort* wb  = ws16 + 4 * SB;   // bf16 weights (4MB)
    ushort* wbq = wb;
    ushort* wbk = wb + 262144;
    ushort* wbv = wb + 524288;
    ushort* wbr = wb + 786432;
    ushort* wb1 = wb + 1048576;
    ushort* wb2 = wb + 1572864;
    float*  ctxf = (float*)(wb + 2097152);       // [B*H,64,64] fp32 (256KB)
    float2* stats = (float2*)(ctxf + 65536);     // [B*C][8] (256KB)
    float2* minv  = stats + (size_t)B_ * C_ * 8; // [B*C] (32KB)
    ushort* vbuf = (ushort*)d_out;               // v lives in d_out
    ushort* hbuf = (ushort*)d_out;               // h: [B*L, 1024] bf16
    float*  yf32 = (float*)b2v;                  // spans b2v+b3v

    const dim3 blk(256);
    const int M = B_ * L_;   // 32768

    // 0) input transposes + weight casts
    transpose_in<<<dim3(L_/64, C_/64, B_), blk, 0, stream>>>(z1, b0v);
    transpose_in<<<dim3(L_/64, C_/64, B_), blk, 0, stream>>>(z2, b1v);
    cvt_bf16<<<dim3(262144/4/256), blk, 0, stream>>>(Wq, wbq, 262144/4);
    cvt_bf16<<<dim3(262144/4/256), blk, 0, stream>>>(Wk, wbk, 262144/4);
    cvt_bf16<<<dim3(262144/4/256), blk, 0, stream>>>(Wv, wbv, 262144/4);
    cvt_bf16<<<dim3(262144/4/256), blk, 0, stream>>>(Wr, wbr, 262144/4);
    cvt_bf16<<<dim3(524288/4/256), blk, 0, stream>>>(W1, wb1, 524288/4);
    cvt_bf16<<<dim3(524288/4/256), blk, 0, stream>>>(W2, wb2, 524288/4);

    // 1) projections (MFMA); q and k stay RAW logits
    conv_mfma<0,false><<<dim3(M/128, C_/128), blk, 0, stream>>>(b0v, wbq, bq, nullptr, b2v, M, C_, C_);
    conv_mfma<0,false><<<dim3(M/128, C_/128), blk, 0, stream>>>(b1v, wbk, bk, nullptr, b3v, M, C_, C_);
    conv_mfma<0,false><<<dim3(M/128, C_/128), blk, 0, stream>>>(b1v, wbv, bv, nullptr, vbuf, M, C_, C_);

    // 2) k-softmax stats (parallel, chunked)
    kstat_chunk<<<dim3(C_/64, B_ * 8), blk, 0, stream>>>(b3v, stats);
    kstat_merge<<<dim3((B_ * C_ + 255) / 256), blk, 0, stream>>>(stats, minv);

    // 3) ctxT = V^T softmax(K)  (softmax fused, fp32 atomics over 8 l-splits)
    zero_kernel<<<dim3(65536/256), blk, 0, stream>>>(ctxf, 65536);
    ctx_accum<<<dim3(8, B_ * H_), blk, 0, stream>>>(b3v, vbuf, minv, ctxf);

    // 4) att = softmax(q) . ctxT^T per head (q-softmax fused); att -> b1v
    att_mfma<<<dim3(L_/128, B_ * H_), blk, 0, stream>>>(b2v, ctxf, b1v);

    // 5) z = Wr@att + br + z1t  -> b2v (q dead)
    conv_mfma<0,true><<<dim3(M/128, C_/128), blk, 0, stream>>>(b1v, wbr, br, b0v, b2v, M, C_, C_);

    // 6) x = LN1(z) -> b3v (k dead)
    ln_row<false><<<dim3(M/4), blk, 0, stream>>>(b2v, g1, be1, b3v, nullptr);

    // 7) h = ELU(W1@x) -> d_out (v dead)
    conv_mfma<1,false><<<dim3(M/128, C2_/128), blk, 0, stream>>>(b3v, wb1, b1, nullptr, hbuf, M, C2_, C_);

    // 8) y = W2@h -> b0v (z1t dead)
    conv_mfma<0,false><<<dim3(M/128, C_/128), blk, 0, stream>>>(hbuf, wb2, b2, nullptr, b0v, M, C_, C2_);

    // 9) LN2 -> fp32 [B*L,C] into b2v+b3v region (z,x dead)
    ln_row<true><<<dim3(M/4), blk, 0, stream>>>(b0v, g2, be2, nullptr, yf32);

    // 10) transpose to [B,C,L] fp32 -> d_out (h dead)
    transpose_out<<<dim3(L_/64, C_/64, B_), blk, 0, stream>>>(yf32, out);
}